// Round 1
// baseline (1247.574 us; speedup 1.0000x reference)
//
#include <hip/hip_runtime.h>
#include <hip/hip_bf16.h>

#define N_NODES 100000
#define N_EDGES 1600000
#define IN_CH 256
#define NHEAD 4
#define CH 64
#define HC 256  // NHEAD*CH
#define NEG_SLOPE 0.2f

// ---------------- fp32 GEMM: Hm = X @ W, [M,256] x [256,256] ----------------
#define BM 64
#define BN 64
#define BK 32

__global__ __launch_bounds__(256) void gemm_xw(const float* __restrict__ X,
                                               const float* __restrict__ W,
                                               float* __restrict__ Hout, int M) {
  __shared__ float xs[BK][BM + 4];   // transposed X tile; rows 16B-aligned
  __shared__ float wsh[BK][BN + 4];
  const int tid = threadIdx.x;
  const int tx = tid & 15;
  const int ty = tid >> 4;
  const int row0 = blockIdx.x * BM;
  const int col0 = blockIdx.y * BN;
  float acc[4][4] = {};

  for (int k0 = 0; k0 < IN_CH; k0 += BK) {
    // X tile: 64 rows x 32 cols = 512 float4, 2 per thread (store transposed)
#pragma unroll
    for (int i = 0; i < 2; ++i) {
      int idx = tid + i * 256;       // 0..511
      int r = idx >> 3;              // 0..63
      int c4 = (idx & 7) << 2;       // 0,4,...,28
      float4 v = make_float4(0.f, 0.f, 0.f, 0.f);
      int gr = row0 + r;
      if (gr < M) v = *reinterpret_cast<const float4*>(X + (size_t)gr * IN_CH + k0 + c4);
      xs[c4 + 0][r] = v.x;
      xs[c4 + 1][r] = v.y;
      xs[c4 + 2][r] = v.z;
      xs[c4 + 3][r] = v.w;
    }
    // W tile: 32 rows x 64 cols = 512 float4, 2 per thread
#pragma unroll
    for (int i = 0; i < 2; ++i) {
      int idx = tid + i * 256;
      int r = idx >> 4;              // 0..31
      int c4 = (idx & 15) << 2;      // 0..60
      float4 v = *reinterpret_cast<const float4*>(W + (size_t)(k0 + r) * HC + col0 + c4);
      *reinterpret_cast<float4*>(&wsh[r][c4]) = v;
    }
    __syncthreads();
#pragma unroll
    for (int k = 0; k < BK; ++k) {
      float a[4], b[4];
#pragma unroll
      for (int i = 0; i < 4; ++i) a[i] = xs[k][ty * 4 + i];
#pragma unroll
      for (int j = 0; j < 4; ++j) b[j] = wsh[k][tx * 4 + j];
#pragma unroll
      for (int i = 0; i < 4; ++i)
#pragma unroll
        for (int j = 0; j < 4; ++j) acc[i][j] += a[i] * b[j];
    }
    __syncthreads();
  }
#pragma unroll
  for (int i = 0; i < 4; ++i) {
    int gr = row0 + ty * 4 + i;
    if (gr < M) {
      float4 v = make_float4(acc[i][0], acc[i][1], acc[i][2], acc[i][3]);
      *reinterpret_cast<float4*>(Hout + (size_t)gr * HC + col0 + tx * 4) = v;
    }
  }
}

// ---------------- per-node attention dots: a_src[n,h], a_dst[n,h] ----------------
__global__ __launch_bounds__(256) void attn_dots(const float* __restrict__ Hm,
                                                 const float* __restrict__ att_src,
                                                 const float* __restrict__ att_dst,
                                                 float* __restrict__ as_out,
                                                 float* __restrict__ ad_out) {
  int node = blockIdx.x * 4 + (threadIdx.x >> 6);
  int lane = threadIdx.x & 63;
  if (node >= N_NODES) return;
  float sv[NHEAD], dv[NHEAD];
#pragma unroll
  for (int h = 0; h < NHEAD; ++h) {
    float v = Hm[(size_t)node * HC + h * CH + lane];
    sv[h] = v * att_src[h * CH + lane];
    dv[h] = v * att_dst[h * CH + lane];
  }
#pragma unroll
  for (int off = 32; off > 0; off >>= 1) {
#pragma unroll
    for (int h = 0; h < NHEAD; ++h) {
      sv[h] += __shfl_down(sv[h], off, 64);
      dv[h] += __shfl_down(dv[h], off, 64);
    }
  }
  if (lane == 0) {
#pragma unroll
    for (int h = 0; h < NHEAD; ++h) {
      as_out[node * NHEAD + h] = sv[h];
      ad_out[node * NHEAD + h] = dv[h];
    }
  }
}

// ---------------- init output with bias ----------------
__global__ void init_out(float* __restrict__ out, const float* __restrict__ bias) {
  int i = blockIdx.x * blockDim.x + threadIdx.x;
  if (i < N_NODES * CH) out[i] = bias[i & (CH - 1)];
}

// ---------------- edge pass 1: softmax denominators ----------------
__global__ __launch_bounds__(256) void edge_denom(const int* __restrict__ esrc,
                                                  const int* __restrict__ edst,
                                                  const float* __restrict__ as_buf,
                                                  const float* __restrict__ ad_buf,
                                                  float* __restrict__ denom) {
  int e = blockIdx.x * blockDim.x + threadIdx.x;
  const int tot = N_EDGES + N_NODES;
  if (e >= tot) return;
  int s, d;
  if (e < N_EDGES) { s = esrc[e]; d = edst[e]; }
  else { s = e - N_EDGES; d = s; }
  float4 a1 = *reinterpret_cast<const float4*>(as_buf + (size_t)s * NHEAD);
  float4 a2 = *reinterpret_cast<const float4*>(ad_buf + (size_t)d * NHEAD);
  float el[NHEAD] = {a1.x + a2.x, a1.y + a2.y, a1.z + a2.z, a1.w + a2.w};
#pragma unroll
  for (int h = 0; h < NHEAD; ++h) {
    float v = el[h];
    v = v > 0.f ? v : NEG_SLOPE * v;
    float w = __expf(v);
    unsafeAtomicAdd(&denom[(size_t)d * NHEAD + h], w);
  }
}

// ---------------- edge pass 2: aggregate (one wave per edge) ----------------
__global__ __launch_bounds__(256) void edge_aggregate(const int* __restrict__ esrc,
                                                      const int* __restrict__ edst,
                                                      const float* __restrict__ as_buf,
                                                      const float* __restrict__ ad_buf,
                                                      const float* __restrict__ denom,
                                                      const float* __restrict__ Hm,
                                                      float* __restrict__ out) {
  int gw = blockIdx.x * 4 + (threadIdx.x >> 6);  // global wave id = edge id
  int lane = threadIdx.x & 63;
  const int tot = N_EDGES + N_NODES;
  if (gw >= tot) return;
  int s, d;
  if (gw < N_EDGES) { s = esrc[gw]; d = edst[gw]; }
  else { s = gw - N_EDGES; d = s; }
  float4 a1 = *reinterpret_cast<const float4*>(as_buf + (size_t)s * NHEAD);
  float4 a2 = *reinterpret_cast<const float4*>(ad_buf + (size_t)d * NHEAD);
  float4 dn = *reinterpret_cast<const float4*>(denom + (size_t)d * NHEAD);
  float el[NHEAD] = {a1.x + a2.x, a1.y + a2.y, a1.z + a2.z, a1.w + a2.w};
  float dnv[NHEAD] = {dn.x, dn.y, dn.z, dn.w};
  float acc = 0.f;
#pragma unroll
  for (int h = 0; h < NHEAD; ++h) {
    float v = el[h];
    v = v > 0.f ? v : NEG_SLOPE * v;
    float alpha = __expf(v) / (dnv[h] + 1e-16f);
    acc += alpha * Hm[(size_t)s * HC + h * CH + lane];
  }
  unsafeAtomicAdd(&out[(size_t)d * CH + lane], acc * 0.25f);
}

extern "C" void kernel_launch(void* const* d_in, const int* in_sizes, int n_in,
                              void* d_out, int out_size, void* d_ws, size_t ws_size,
                              hipStream_t stream) {
  const float* x       = (const float*)d_in[0];
  const int*   eidx    = (const int*)d_in[1];
  const float* W       = (const float*)d_in[2];
  const float* att_src = (const float*)d_in[3];
  const float* att_dst = (const float*)d_in[4];
  const float* bias    = (const float*)d_in[5];
  float* out = (float*)d_out;

  float* Hm     = (float*)d_ws;                               // N*256
  float* as_buf = Hm + (size_t)N_NODES * HC;                  // N*4
  float* ad_buf = as_buf + (size_t)N_NODES * NHEAD;           // N*4
  float* denom  = ad_buf + (size_t)N_NODES * NHEAD;           // N*4

  const int* esrc = eidx;
  const int* edst = eidx + N_EDGES;

  hipMemsetAsync(denom, 0, (size_t)N_NODES * NHEAD * sizeof(float), stream);

  init_out<<<(N_NODES * CH + 255) / 256, 256, 0, stream>>>(out, bias);

  dim3 ggrid((N_NODES + BM - 1) / BM, HC / BN);
  gemm_xw<<<ggrid, 256, 0, stream>>>(x, W, Hm, N_NODES);

  attn_dots<<<N_NODES / 4, 256, 0, stream>>>(Hm, att_src, att_dst, as_buf, ad_buf);

  const int tot = N_EDGES + N_NODES;
  edge_denom<<<(tot + 255) / 256, 256, 0, stream>>>(esrc, edst, as_buf, ad_buf, denom);

  edge_aggregate<<<tot, 256, 0, stream>>>(esrc, edst, as_buf, ad_buf, denom, Hm, out);
}

// Round 2
// 632.185 us; speedup vs baseline: 1.9734x; 1.9734x over previous
//
#include <hip/hip_runtime.h>

#define N_NODES 100000
#define N_EDGES 1600000
#define TOT (N_EDGES + N_NODES)
#define IN_CH 256
#define NHEAD 4
#define CH 64
#define HC 256
#define NEG_SLOPE 0.2f

// ---------------- fp32 GEMM + fused attention dots ----------------
// Block (bx, h): rows bx*64..+63, cols h*64..+63 (one full head per block).
#define BM 64
#define BN 64
#define BK 32

__global__ __launch_bounds__(256) void gemm_fused(const float* __restrict__ X,
                                                  const float* __restrict__ W,
                                                  const float* __restrict__ att_src,
                                                  const float* __restrict__ att_dst,
                                                  float* __restrict__ Hout,
                                                  float* __restrict__ as_out,
                                                  float* __restrict__ ad_out, int M) {
  __shared__ float xs[BK][BM + 4];
  __shared__ float wsh[BK][BN + 4];
  const int tid = threadIdx.x;
  const int tx = tid & 15;
  const int ty = tid >> 4;
  const int row0 = blockIdx.x * BM;
  const int col0 = blockIdx.y * BN;  // head = blockIdx.y
  float acc[4][4] = {};

  for (int k0 = 0; k0 < IN_CH; k0 += BK) {
#pragma unroll
    for (int i = 0; i < 2; ++i) {
      int idx = tid + i * 256;
      int r = idx >> 3;
      int c4 = (idx & 7) << 2;
      float4 v = make_float4(0.f, 0.f, 0.f, 0.f);
      int gr = row0 + r;
      if (gr < M) v = *reinterpret_cast<const float4*>(X + (size_t)gr * IN_CH + k0 + c4);
      xs[c4 + 0][r] = v.x;
      xs[c4 + 1][r] = v.y;
      xs[c4 + 2][r] = v.z;
      xs[c4 + 3][r] = v.w;
    }
#pragma unroll
    for (int i = 0; i < 2; ++i) {
      int idx = tid + i * 256;
      int r = idx >> 4;
      int c4 = (idx & 15) << 2;
      float4 v = *reinterpret_cast<const float4*>(W + (size_t)(k0 + r) * HC + col0 + c4);
      *reinterpret_cast<float4*>(&wsh[r][c4]) = v;
    }
    __syncthreads();
#pragma unroll
    for (int k = 0; k < BK; ++k) {
      float a[4], b[4];
#pragma unroll
      for (int i = 0; i < 4; ++i) a[i] = xs[k][ty * 4 + i];
#pragma unroll
      for (int j = 0; j < 4; ++j) b[j] = wsh[k][tx * 4 + j];
#pragma unroll
      for (int i = 0; i < 4; ++i)
#pragma unroll
        for (int j = 0; j < 4; ++j) acc[i][j] += a[i] * b[j];
    }
    __syncthreads();
  }

  // store H tile
#pragma unroll
  for (int i = 0; i < 4; ++i) {
    int gr = row0 + ty * 4 + i;
    if (gr < M) {
      float4 v = make_float4(acc[i][0], acc[i][1], acc[i][2], acc[i][3]);
      *reinterpret_cast<float4*>(Hout + (size_t)gr * HC + col0 + tx * 4) = v;
    }
  }

  // fused attention dots: row-wise dot of acc with att vectors, reduce over tx
  float asv[4], adv[4];
#pragma unroll
  for (int j = 0; j < 4; ++j) {
    asv[j] = att_src[col0 + tx * 4 + j];
    adv[j] = att_dst[col0 + tx * 4 + j];
  }
#pragma unroll
  for (int i = 0; i < 4; ++i) {
    float ss = 0.f, dd = 0.f;
#pragma unroll
    for (int j = 0; j < 4; ++j) {
      ss += acc[i][j] * asv[j];
      dd += acc[i][j] * adv[j];
    }
#pragma unroll
    for (int off = 1; off < 16; off <<= 1) {
      ss += __shfl_xor(ss, off, 16);
      dd += __shfl_xor(dd, off, 16);
    }
    int gr = row0 + ty * 4 + i;
    if (tx == 0 && gr < M) {
      as_out[(size_t)gr * NHEAD + blockIdx.y] = ss;
      ad_out[(size_t)gr * NHEAD + blockIdx.y] = dd;
    }
  }
}

// ---------------- CSR build ----------------
__global__ __launch_bounds__(256) void count_deg(const int* __restrict__ edst,
                                                 int* __restrict__ deg) {
  int e = blockIdx.x * 256 + threadIdx.x;
  if (e >= TOT) return;
  int d = (e < N_EDGES) ? edst[e] : (e - N_EDGES);
  atomicAdd(&deg[d], 1);
}

// block scans 1024 elements (4/thread)
__global__ __launch_bounds__(256) void scan1(const int* __restrict__ deg,
                                             int* __restrict__ rp,
                                             int* __restrict__ bsum) {
  __shared__ int sh[256];
  int t = threadIdx.x;
  int base = blockIdx.x * 1024 + t * 4;
  int v[4];
#pragma unroll
  for (int i = 0; i < 4; ++i) v[i] = (base + i < N_NODES) ? deg[base + i] : 0;
  int tsum = v[0] + v[1] + v[2] + v[3];
  sh[t] = tsum;
  __syncthreads();
  for (int off = 1; off < 256; off <<= 1) {
    int x = (t >= off) ? sh[t - off] : 0;
    __syncthreads();
    sh[t] += x;
    __syncthreads();
  }
  if (t == 255) bsum[blockIdx.x] = sh[255];
  int run = sh[t] - tsum;  // exclusive prefix within block
#pragma unroll
  for (int i = 0; i < 4; ++i) {
    if (base + i < N_NODES) rp[base + i] = run;
    run += v[i];
  }
}

#define NBLK1 ((N_NODES + 1023) / 1024)  // 98

__global__ __launch_bounds__(128) void scan2(const int* __restrict__ bsum,
                                             int* __restrict__ boff) {
  __shared__ int sh[128];
  int t = threadIdx.x;
  int own = (t < NBLK1) ? bsum[t] : 0;
  sh[t] = own;
  __syncthreads();
  for (int off = 1; off < 128; off <<= 1) {
    int x = (t >= off) ? sh[t - off] : 0;
    __syncthreads();
    sh[t] += x;
    __syncthreads();
  }
  boff[t] = sh[t] - own;  // exclusive
}

__global__ __launch_bounds__(256) void scan3(int* __restrict__ rp,
                                             const int* __restrict__ boff,
                                             int* __restrict__ cursor) {
  int idx = blockIdx.x * 256 + threadIdx.x;
  if (idx < N_NODES) {
    int v = rp[idx] + boff[idx >> 10];
    rp[idx] = v;
    cursor[idx] = v;
  }
  if (idx == 0) rp[N_NODES] = TOT;
}

__global__ __launch_bounds__(256) void scatter_edges(const int* __restrict__ esrc,
                                                     const int* __restrict__ edst,
                                                     int* __restrict__ cursor,
                                                     int* __restrict__ csr_src) {
  int e = blockIdx.x * 256 + threadIdx.x;
  if (e >= TOT) return;
  int s, d;
  if (e < N_EDGES) { s = esrc[e]; d = edst[e]; }
  else { s = e - N_EDGES; d = s; }
  int p = atomicAdd(&cursor[d], 1);
  csr_src[p] = s;
}

// ---------------- fused softmax + aggregation: one wave per node ----------------
__global__ __launch_bounds__(256) void aggregate(const int* __restrict__ rp,
                                                 const int* __restrict__ csr_src,
                                                 const float* __restrict__ as_buf,
                                                 const float* __restrict__ ad_buf,
                                                 const float* __restrict__ Hm,
                                                 const float* __restrict__ bias,
                                                 float* __restrict__ out) {
  int n = blockIdx.x * 4 + (threadIdx.x >> 6);
  int lane = threadIdx.x & 63;
  if (n >= N_NODES) return;
  int beg = rp[n], end = rp[n + 1];
  float4 adv = *reinterpret_cast<const float4*>(ad_buf + (size_t)n * NHEAD);
  float acc0 = 0.f, acc1 = 0.f, acc2 = 0.f, acc3 = 0.f;
  float den0 = 0.f, den1 = 0.f, den2 = 0.f, den3 = 0.f;
  int s_next = (beg < end) ? csr_src[beg] : 0;
  for (int j = beg; j < end; ++j) {
    int s = s_next;
    if (j + 1 < end) s_next = csr_src[j + 1];
    float4 asv = *reinterpret_cast<const float4*>(as_buf + (size_t)s * NHEAD);
    const float* hrow = Hm + (size_t)s * HC;
    float h0 = hrow[lane];
    float h1 = hrow[CH + lane];
    float h2 = hrow[2 * CH + lane];
    float h3 = hrow[3 * CH + lane];
    float e0 = asv.x + adv.x; e0 = e0 > 0.f ? e0 : NEG_SLOPE * e0;
    float e1 = asv.y + adv.y; e1 = e1 > 0.f ? e1 : NEG_SLOPE * e1;
    float e2 = asv.z + adv.z; e2 = e2 > 0.f ? e2 : NEG_SLOPE * e2;
    float e3 = asv.w + adv.w; e3 = e3 > 0.f ? e3 : NEG_SLOPE * e3;
    float w0 = __expf(e0), w1 = __expf(e1), w2 = __expf(e2), w3 = __expf(e3);
    den0 += w0; den1 += w1; den2 += w2; den3 += w3;
    acc0 += w0 * h0; acc1 += w1 * h1; acc2 += w2 * h2; acc3 += w3 * h3;
  }
  float r = acc0 / (den0 + 1e-16f) + acc1 / (den1 + 1e-16f) +
            acc2 / (den2 + 1e-16f) + acc3 / (den3 + 1e-16f);
  out[(size_t)n * CH + lane] = 0.25f * r + bias[lane];
}

extern "C" void kernel_launch(void* const* d_in, const int* in_sizes, int n_in,
                              void* d_out, int out_size, void* d_ws, size_t ws_size,
                              hipStream_t stream) {
  const float* x       = (const float*)d_in[0];
  const int*   eidx    = (const int*)d_in[1];
  const float* W       = (const float*)d_in[2];
  const float* att_src = (const float*)d_in[3];
  const float* att_dst = (const float*)d_in[4];
  const float* bias    = (const float*)d_in[5];
  float* out = (float*)d_out;

  float* Hm     = (float*)d_ws;                              // 25,600,000 f
  float* as_buf = Hm + (size_t)N_NODES * HC;                 // 400,000 f
  float* ad_buf = as_buf + (size_t)N_NODES * NHEAD;          // 400,000 f
  int*   deg    = (int*)(ad_buf + (size_t)N_NODES * NHEAD);  // 100,000 i (reused as cursor)
  int*   rp     = deg + N_NODES;                             // 100,001 i
  int*   bsum   = rp + N_NODES + 1;                          // 128 i
  int*   boff   = bsum + 128;                                // 128 i
  int*   csr    = boff + 128;                                // 1,700,000 i

  const int* esrc = eidx;
  const int* edst = eidx + N_EDGES;

  // GEMM + attention dots (independent of CSR build)
  dim3 ggrid((N_NODES + BM - 1) / BM, NHEAD);
  gemm_fused<<<ggrid, 256, 0, stream>>>(x, W, att_src, att_dst, Hm, as_buf, ad_buf, N_NODES);

  // CSR build
  hipMemsetAsync(deg, 0, (size_t)N_NODES * sizeof(int), stream);
  count_deg<<<(TOT + 255) / 256, 256, 0, stream>>>(edst, deg);
  scan1<<<NBLK1, 256, 0, stream>>>(deg, rp, bsum);
  scan2<<<1, 128, 0, stream>>>(bsum, boff);
  scan3<<<(N_NODES + 255) / 256, 256, 0, stream>>>(rp, boff, deg /*cursor*/);
  scatter_edges<<<(TOT + 255) / 256, 256, 0, stream>>>(esrc, edst, deg /*cursor*/, csr);

  // fused softmax + aggregation, no atomics
  aggregate<<<(N_NODES + 3) / 4, 256, 0, stream>>>(rp, csr, as_buf, ad_buf, Hm, bias, out);
}

// Round 3
// 447.073 us; speedup vs baseline: 2.7905x; 1.4141x over previous
//
#include <hip/hip_runtime.h>

#define N_NODES 100000
#define N_EDGES 1600000
#define TOT (N_EDGES + N_NODES)
#define IN_CH 256
#define NHEAD 4
#define CH 64
#define HC 256
#define NEG_SLOPE 0.2f

typedef _Float16 half8 __attribute__((ext_vector_type(8)));
typedef float f32x4 __attribute__((ext_vector_type(4)));
typedef unsigned short ushort_t;
typedef unsigned int uint_t;

static __device__ __forceinline__ ushort_t f2h(float f) {
  _Float16 h = (_Float16)f;
  return __builtin_bit_cast(ushort_t, h);
}
static __device__ __forceinline__ float h2f(ushort_t u) {
  _Float16 h = __builtin_bit_cast(_Float16, u);
  return (float)h;
}

// ---------------- W fp32 [K=256][N=256] -> Wt fp16 [N][K] ----------------
__global__ __launch_bounds__(256) void conv_w(const float* __restrict__ W,
                                              ushort_t* __restrict__ Wt) {
  int t = threadIdx.x;  // n index
  for (int k0 = 0; k0 < IN_CH; k0 += 4) {
    ushort4 u;
    u.x = f2h(W[(size_t)(k0 + 0) * HC + t]);
    u.y = f2h(W[(size_t)(k0 + 1) * HC + t]);
    u.z = f2h(W[(size_t)(k0 + 2) * HC + t]);
    u.w = f2h(W[(size_t)(k0 + 3) * HC + t]);
    *reinterpret_cast<ushort4*>(&Wt[(size_t)t * IN_CH + k0]) = u;
  }
}

// ---------------- MFMA GEMM: Hmp = f16(X @ W), packed; fused attn dots ----------------
// Block: 128 rows x 256 cols (all heads). 4 waves, each 32 rows x 256 cols.
#define GBM 128
#define GBK 32
#define LDA 40  // 32 + 8 pad (halfs)

__global__ __launch_bounds__(256) void gemm_mfma(const float* __restrict__ X,
                                                 const ushort_t* __restrict__ Wt,
                                                 const float* __restrict__ att_src,
                                                 const float* __restrict__ att_dst,
                                                 uint2* __restrict__ Hmp,
                                                 float* __restrict__ as_out,
                                                 float* __restrict__ ad_out, int M) {
  __shared__ __align__(16) ushort_t As[GBM][LDA];
  __shared__ __align__(16) ushort_t Bs[HC][LDA];
  const int tid = threadIdx.x;
  const int lane = tid & 63;
  const int wid = tid >> 6;     // wave row-block 0..3
  const int l16 = lane & 15;
  const int lhi = lane >> 4;
  const int row0 = blockIdx.x * GBM;

  f32x4 acc[2][16] = {};

  for (int k0 = 0; k0 < IN_CH; k0 += GBK) {
    // stage A: thread t -> row t>>1, 16 cols at (t&1)*16
    {
      int r = tid >> 1;
      int c0 = (tid & 1) * 16;
      int gr = row0 + r;
      float4 v0, v1, v2, v3;
      if (gr < M) {
        const float4* p = reinterpret_cast<const float4*>(X + (size_t)gr * IN_CH + k0 + c0);
        v0 = p[0]; v1 = p[1]; v2 = p[2]; v3 = p[3];
      } else {
        v0 = v1 = v2 = v3 = make_float4(0.f, 0.f, 0.f, 0.f);
      }
      ushort_t* dst = &As[r][c0];
      dst[0] = f2h(v0.x);  dst[1] = f2h(v0.y);  dst[2] = f2h(v0.z);  dst[3] = f2h(v0.w);
      dst[4] = f2h(v1.x);  dst[5] = f2h(v1.y);  dst[6] = f2h(v1.z);  dst[7] = f2h(v1.w);
      dst[8] = f2h(v2.x);  dst[9] = f2h(v2.y);  dst[10] = f2h(v2.z); dst[11] = f2h(v2.w);
      dst[12] = f2h(v3.x); dst[13] = f2h(v3.y); dst[14] = f2h(v3.z); dst[15] = f2h(v3.w);
    }
    // stage B: thread t -> n-row t, 32 k values
    {
      const uint4* p = reinterpret_cast<const uint4*>(Wt + (size_t)tid * IN_CH + k0);
      uint4 w0 = p[0], w1 = p[1];  // 32 halfs = 64B
      *reinterpret_cast<uint4*>(&Bs[tid][0]) = w0;
      *reinterpret_cast<uint4*>(&Bs[tid][8]) = w1;
      p = reinterpret_cast<const uint4*>(Wt + (size_t)tid * IN_CH + k0 + 16);
      uint4 w2 = p[0], w3 = p[1];
      *reinterpret_cast<uint4*>(&Bs[tid][16]) = w2;
      *reinterpret_cast<uint4*>(&Bs[tid][24]) = w3;
    }
    __syncthreads();
    half8 a0 = *reinterpret_cast<const half8*>(&As[wid * 32 + l16][lhi * 8]);
    half8 a1 = *reinterpret_cast<const half8*>(&As[wid * 32 + 16 + l16][lhi * 8]);
#pragma unroll
    for (int n = 0; n < 16; ++n) {
      half8 b = *reinterpret_cast<const half8*>(&Bs[n * 16 + l16][lhi * 8]);
      acc[0][n] = __builtin_amdgcn_mfma_f32_16x16x32_f16(a0, b, acc[0][n], 0, 0, 0);
      acc[1][n] = __builtin_amdgcn_mfma_f32_16x16x32_f16(a1, b, acc[1][n], 0, 0, 0);
    }
    __syncthreads();
  }

  // attention vectors: col = n*16 + l16 maps to head n>>2, channel (n&3)*16+l16
  float attS[16], attD[16];
#pragma unroll
  for (int n = 0; n < 16; ++n) {
    attS[n] = att_src[n * 16 + l16];
    attD[n] = att_dst[n * 16 + l16];
  }

#pragma unroll
  for (int m = 0; m < 2; ++m) {
#pragma unroll
    for (int r = 0; r < 4; ++r) {
      int grow = row0 + wid * 32 + m * 16 + lhi * 4 + r;
      if (grow < M) {
        // pack h (fp16) : uint2 {heads01, heads23} per channel-lane
#pragma unroll
        for (int n2 = 0; n2 < 4; ++n2) {
          uint_t pk01 = (uint_t)f2h(acc[m][n2][r]) | ((uint_t)f2h(acc[m][n2 + 4][r]) << 16);
          uint_t pk23 = (uint_t)f2h(acc[m][n2 + 8][r]) | ((uint_t)f2h(acc[m][n2 + 12][r]) << 16);
          Hmp[(size_t)grow * 64 + n2 * 16 + l16] = make_uint2(pk01, pk23);
        }
        // fused attention dots
        float s[4] = {0.f, 0.f, 0.f, 0.f}, d[4] = {0.f, 0.f, 0.f, 0.f};
#pragma unroll
        for (int h = 0; h < 4; ++h)
#pragma unroll
          for (int j = 0; j < 4; ++j) {
            s[h] += acc[m][h * 4 + j][r] * attS[h * 4 + j];
            d[h] += acc[m][h * 4 + j][r] * attD[h * 4 + j];
          }
#pragma unroll
        for (int off = 1; off < 16; off <<= 1)
#pragma unroll
          for (int h = 0; h < 4; ++h) {
            s[h] += __shfl_xor(s[h], off, 16);
            d[h] += __shfl_xor(d[h], off, 16);
          }
        if (l16 == 0) {
#pragma unroll
          for (int h = 0; h < 4; ++h) {
            as_out[(size_t)grow * 4 + h] = s[h];
            ad_out[(size_t)grow * 4 + h] = d[h];
          }
        }
      }
    }
  }
}

// ---------------- CSR build ----------------
__global__ __launch_bounds__(256) void count_deg(const int* __restrict__ edst,
                                                 int* __restrict__ deg) {
  int e = blockIdx.x * 256 + threadIdx.x;
  if (e >= TOT) return;
  int d = (e < N_EDGES) ? edst[e] : (e - N_EDGES);
  atomicAdd(&deg[d], 1);
}

__global__ __launch_bounds__(256) void scan1(const int* __restrict__ deg,
                                             int* __restrict__ rp,
                                             int* __restrict__ bsum) {
  __shared__ int sh[256];
  int t = threadIdx.x;
  int base = blockIdx.x * 1024 + t * 4;
  int v[4];
#pragma unroll
  for (int i = 0; i < 4; ++i) v[i] = (base + i < N_NODES) ? deg[base + i] : 0;
  int tsum = v[0] + v[1] + v[2] + v[3];
  sh[t] = tsum;
  __syncthreads();
  for (int off = 1; off < 256; off <<= 1) {
    int x = (t >= off) ? sh[t - off] : 0;
    __syncthreads();
    sh[t] += x;
    __syncthreads();
  }
  if (t == 255) bsum[blockIdx.x] = sh[255];
  int run = sh[t] - tsum;
#pragma unroll
  for (int i = 0; i < 4; ++i) {
    if (base + i < N_NODES) rp[base + i] = run;
    run += v[i];
  }
}

#define NBLK1 ((N_NODES + 1023) / 1024)  // 98

__global__ __launch_bounds__(128) void scan2(const int* __restrict__ bsum,
                                             int* __restrict__ boff) {
  __shared__ int sh[128];
  int t = threadIdx.x;
  int own = (t < NBLK1) ? bsum[t] : 0;
  sh[t] = own;
  __syncthreads();
  for (int off = 1; off < 128; off <<= 1) {
    int x = (t >= off) ? sh[t - off] : 0;
    __syncthreads();
    sh[t] += x;
    __syncthreads();
  }
  boff[t] = sh[t] - own;
}

__global__ __launch_bounds__(256) void scan3(int* __restrict__ rp,
                                             const int* __restrict__ boff,
                                             int* __restrict__ cursor) {
  int idx = blockIdx.x * 256 + threadIdx.x;
  if (idx < N_NODES) {
    int v = rp[idx] + boff[idx >> 10];
    rp[idx] = v;
    cursor[idx] = v;
  }
  if (idx == 0) rp[N_NODES] = TOT;
}

__global__ __launch_bounds__(256) void scatter_edges(const int* __restrict__ esrc,
                                                     const int* __restrict__ edst,
                                                     int* __restrict__ cursor,
                                                     int* __restrict__ csr_src) {
  int e = blockIdx.x * 256 + threadIdx.x;
  if (e >= TOT) return;
  int s, d;
  if (e < N_EDGES) { s = esrc[e]; d = edst[e]; }
  else { s = e - N_EDGES; d = s; }
  int p = atomicAdd(&cursor[d], 1);
  csr_src[p] = s;
}

// ---------------- fused softmax + aggregation: one wave per node ----------------
__global__ __launch_bounds__(256) void aggregate(const int* __restrict__ rp,
                                                 const int* __restrict__ csr_src,
                                                 const float* __restrict__ as_buf,
                                                 const float* __restrict__ ad_buf,
                                                 const uint2* __restrict__ Hp,
                                                 const float* __restrict__ bias,
                                                 float* __restrict__ out) {
  int n = blockIdx.x * 4 + (threadIdx.x >> 6);
  int lane = threadIdx.x & 63;
  if (n >= N_NODES) return;
  int beg = rp[n], end = rp[n + 1];
  float4 adv = *reinterpret_cast<const float4*>(ad_buf + (size_t)n * NHEAD);
  float acc0 = 0.f, acc1 = 0.f, acc2 = 0.f, acc3 = 0.f;
  float den0 = 0.f, den1 = 0.f, den2 = 0.f, den3 = 0.f;
  int s_next = (beg < end) ? csr_src[beg] : 0;
  for (int j = beg; j < end; ++j) {
    int s = s_next;
    if (j + 1 < end) s_next = csr_src[j + 1];
    float4 asv = *reinterpret_cast<const float4*>(as_buf + (size_t)s * NHEAD);
    uint2 hv = Hp[(size_t)s * 64 + lane];
    float ha = h2f((ushort_t)(hv.x & 0xffffu));
    float hb = h2f((ushort_t)(hv.x >> 16));
    float hc = h2f((ushort_t)(hv.y & 0xffffu));
    float hd = h2f((ushort_t)(hv.y >> 16));
    float e0 = asv.x + adv.x; e0 = e0 > 0.f ? e0 : NEG_SLOPE * e0;
    float e1 = asv.y + adv.y; e1 = e1 > 0.f ? e1 : NEG_SLOPE * e1;
    float e2 = asv.z + adv.z; e2 = e2 > 0.f ? e2 : NEG_SLOPE * e2;
    float e3 = asv.w + adv.w; e3 = e3 > 0.f ? e3 : NEG_SLOPE * e3;
    float w0 = __expf(e0), w1 = __expf(e1), w2 = __expf(e2), w3 = __expf(e3);
    den0 += w0; den1 += w1; den2 += w2; den3 += w3;
    acc0 += w0 * ha; acc1 += w1 * hb; acc2 += w2 * hc; acc3 += w3 * hd;
  }
  float r = acc0 / (den0 + 1e-16f) + acc1 / (den1 + 1e-16f) +
            acc2 / (den2 + 1e-16f) + acc3 / (den3 + 1e-16f);
  out[(size_t)n * CH + lane] = 0.25f * r + bias[lane];
}

extern "C" void kernel_launch(void* const* d_in, const int* in_sizes, int n_in,
                              void* d_out, int out_size, void* d_ws, size_t ws_size,
                              hipStream_t stream) {
  const float* x       = (const float*)d_in[0];
  const int*   eidx    = (const int*)d_in[1];
  const float* W       = (const float*)d_in[2];
  const float* att_src = (const float*)d_in[3];
  const float* att_dst = (const float*)d_in[4];
  const float* bias    = (const float*)d_in[5];
  float* out = (float*)d_out;

  uint2*    Hmp    = (uint2*)d_ws;                               // N*64 uint2 = 51.2 MB
  float*    as_buf = (float*)(Hmp + (size_t)N_NODES * 64);       // N*4
  float*    ad_buf = as_buf + (size_t)N_NODES * NHEAD;           // N*4
  ushort_t* Wt     = (ushort_t*)(ad_buf + (size_t)N_NODES * NHEAD);  // 65536
  int*      deg    = (int*)(Wt + 65536);                         // N (reused as cursor)
  int*      rp     = deg + N_NODES;                              // N+1
  int*      bsum   = rp + N_NODES + 1;                           // 128
  int*      boff   = bsum + 128;                                 // 128
  int*      csr    = boff + 128;                                 // TOT

  const int* esrc = eidx;
  const int* edst = eidx + N_EDGES;

  conv_w<<<1, 256, 0, stream>>>(W, Wt);

  dim3 ggrid((N_NODES + GBM - 1) / GBM);
  gemm_mfma<<<ggrid, 256, 0, stream>>>(x, Wt, att_src, att_dst, Hmp, as_buf, ad_buf, N_NODES);

  hipMemsetAsync(deg, 0, (size_t)N_NODES * sizeof(int), stream);
  count_deg<<<(TOT + 255) / 256, 256, 0, stream>>>(edst, deg);
  scan1<<<NBLK1, 256, 0, stream>>>(deg, rp, bsum);
  scan2<<<1, 128, 0, stream>>>(bsum, boff);
  scan3<<<(N_NODES + 255) / 256, 256, 0, stream>>>(rp, boff, deg /*cursor*/);
  scatter_edges<<<(TOT + 255) / 256, 256, 0, stream>>>(esrc, edst, deg /*cursor*/, csr);

  aggregate<<<(N_NODES + 3) / 4, 256, 0, stream>>>(rp, csr, as_buf, ad_buf, Hmp, bias, out);
}

// Round 4
// 374.513 us; speedup vs baseline: 3.3312x; 1.1937x over previous
//
#include <hip/hip_runtime.h>

#define N_NODES 100000
#define N_EDGES 1600000
#define TOT (N_EDGES + N_NODES)
#define IN_CH 256
#define NHEAD 4
#define CH 64
#define HC 256
#define NEG_SLOPE 0.2f

typedef _Float16 half8 __attribute__((ext_vector_type(8)));
typedef _Float16 h2v __attribute__((ext_vector_type(2)));
typedef float f32x4 __attribute__((ext_vector_type(4)));
typedef unsigned short ushort_t;
typedef unsigned int uint_t;

static __device__ __forceinline__ ushort_t f2h(float f) {
  _Float16 h = (_Float16)f;
  return __builtin_bit_cast(ushort_t, h);
}

// ---------------- W fp32 [K=256][N=256] -> Wt fp16 [N][K] ----------------
__global__ __launch_bounds__(256) void conv_w(const float* __restrict__ W,
                                              ushort_t* __restrict__ Wt) {
  int n = blockIdx.x * 4 + (threadIdx.x >> 6);
  int k0 = (threadIdx.x & 63) * 4;
  ushort4 u;
  u.x = f2h(W[(size_t)(k0 + 0) * HC + n]);
  u.y = f2h(W[(size_t)(k0 + 1) * HC + n]);
  u.z = f2h(W[(size_t)(k0 + 2) * HC + n]);
  u.w = f2h(W[(size_t)(k0 + 3) * HC + n]);
  *reinterpret_cast<ushort4*>(&Wt[(size_t)n * IN_CH + k0]) = u;
}

// ---------------- MFMA GEMM: Hmp = f16(X @ W), packed; fused attn dots ----------------
#define GBM 128
#define GBK 32
#define LDA 40  // 32 + 8 pad (halfs); row stride 80B (16B-aligned)

__global__ __launch_bounds__(256) void gemm_mfma(const float* __restrict__ X,
                                                 const ushort_t* __restrict__ Wt,
                                                 const float* __restrict__ att_src,
                                                 const float* __restrict__ att_dst,
                                                 uint2* __restrict__ Hmp,
                                                 float* __restrict__ as_out,
                                                 float* __restrict__ ad_out, int M) {
  __shared__ __align__(16) ushort_t As[GBM][LDA];
  __shared__ __align__(16) ushort_t Bs[HC][LDA];
  const int tid = threadIdx.x;
  const int lane = tid & 63;
  const int wid = tid >> 6;
  const int l16 = lane & 15;
  const int lhi = lane >> 4;
  const int row0 = blockIdx.x * GBM;

  f32x4 acc[2][16] = {};

  for (int k0 = 0; k0 < IN_CH; k0 += GBK) {
    // stage A: thread t -> row t>>1, 16 cols at (t&1)*16, via pkrtz + b128 writes
    {
      int r = tid >> 1;
      int c0 = (tid & 1) * 16;
      int gr = row0 + r;
      float4 v0, v1, v2, v3;
      if (gr < M) {
        const float4* p = reinterpret_cast<const float4*>(X + (size_t)gr * IN_CH + k0 + c0);
        v0 = p[0]; v1 = p[1]; v2 = p[2]; v3 = p[3];
      } else {
        v0 = v1 = v2 = v3 = make_float4(0.f, 0.f, 0.f, 0.f);
      }
      uint4 u0, u1;
      u0.x = __builtin_bit_cast(uint_t, __builtin_amdgcn_cvt_pkrtz(v0.x, v0.y));
      u0.y = __builtin_bit_cast(uint_t, __builtin_amdgcn_cvt_pkrtz(v0.z, v0.w));
      u0.z = __builtin_bit_cast(uint_t, __builtin_amdgcn_cvt_pkrtz(v1.x, v1.y));
      u0.w = __builtin_bit_cast(uint_t, __builtin_amdgcn_cvt_pkrtz(v1.z, v1.w));
      u1.x = __builtin_bit_cast(uint_t, __builtin_amdgcn_cvt_pkrtz(v2.x, v2.y));
      u1.y = __builtin_bit_cast(uint_t, __builtin_amdgcn_cvt_pkrtz(v2.z, v2.w));
      u1.z = __builtin_bit_cast(uint_t, __builtin_amdgcn_cvt_pkrtz(v3.x, v3.y));
      u1.w = __builtin_bit_cast(uint_t, __builtin_amdgcn_cvt_pkrtz(v3.z, v3.w));
      *reinterpret_cast<uint4*>(&As[r][c0]) = u0;
      *reinterpret_cast<uint4*>(&As[r][c0 + 8]) = u1;
    }
    // stage B: thread t -> n-row t, 32 k values
    {
      const uint4* p = reinterpret_cast<const uint4*>(Wt + (size_t)tid * IN_CH + k0);
      uint4 w0 = p[0], w1 = p[1];
      *reinterpret_cast<uint4*>(&Bs[tid][0]) = w0;
      *reinterpret_cast<uint4*>(&Bs[tid][8]) = w1;
      p = reinterpret_cast<const uint4*>(Wt + (size_t)tid * IN_CH + k0 + 16);
      uint4 w2 = p[0], w3 = p[1];
      *reinterpret_cast<uint4*>(&Bs[tid][16]) = w2;
      *reinterpret_cast<uint4*>(&Bs[tid][24]) = w3;
    }
    __syncthreads();
    half8 a0 = *reinterpret_cast<const half8*>(&As[wid * 32 + l16][lhi * 8]);
    half8 a1 = *reinterpret_cast<const half8*>(&As[wid * 32 + 16 + l16][lhi * 8]);
#pragma unroll
    for (int n = 0; n < 16; ++n) {
      half8 b = *reinterpret_cast<const half8*>(&Bs[n * 16 + l16][lhi * 8]);
      acc[0][n] = __builtin_amdgcn_mfma_f32_16x16x32_f16(a0, b, acc[0][n], 0, 0, 0);
      acc[1][n] = __builtin_amdgcn_mfma_f32_16x16x32_f16(a1, b, acc[1][n], 0, 0, 0);
    }
    __syncthreads();
  }

  float attS[16], attD[16];
#pragma unroll
  for (int n = 0; n < 16; ++n) {
    attS[n] = att_src[n * 16 + l16];
    attD[n] = att_dst[n * 16 + l16];
  }

#pragma unroll
  for (int m = 0; m < 2; ++m) {
#pragma unroll
    for (int r = 0; r < 4; ++r) {
      int grow = row0 + wid * 32 + m * 16 + lhi * 4 + r;
      if (grow < M) {
#pragma unroll
        for (int n2 = 0; n2 < 4; ++n2) {
          uint_t pk01 = __builtin_bit_cast(uint_t,
              __builtin_amdgcn_cvt_pkrtz(acc[m][n2][r], acc[m][n2 + 4][r]));
          uint_t pk23 = __builtin_bit_cast(uint_t,
              __builtin_amdgcn_cvt_pkrtz(acc[m][n2 + 8][r], acc[m][n2 + 12][r]));
          Hmp[(size_t)grow * 64 + n2 * 16 + l16] = make_uint2(pk01, pk23);
        }
        float s[4] = {0.f, 0.f, 0.f, 0.f}, d[4] = {0.f, 0.f, 0.f, 0.f};
#pragma unroll
        for (int h = 0; h < 4; ++h)
#pragma unroll
          for (int j = 0; j < 4; ++j) {
            s[h] += acc[m][h * 4 + j][r] * attS[h * 4 + j];
            d[h] += acc[m][h * 4 + j][r] * attD[h * 4 + j];
          }
#pragma unroll
        for (int off = 1; off < 16; off <<= 1)
#pragma unroll
          for (int h = 0; h < 4; ++h) {
            s[h] += __shfl_xor(s[h], off, 16);
            d[h] += __shfl_xor(d[h], off, 16);
          }
        if (l16 == 0) {
#pragma unroll
          for (int h = 0; h < 4; ++h) {
            as_out[(size_t)grow * 4 + h] = s[h];
            ad_out[(size_t)grow * 4 + h] = d[h];
          }
        }
      }
    }
  }
}

// ---------------- CSR build ----------------
__global__ __launch_bounds__(256) void count_deg(const int* __restrict__ edst,
                                                 int* __restrict__ deg) {
  int e = blockIdx.x * 256 + threadIdx.x;
  if (e >= TOT) return;
  int d = (e < N_EDGES) ? edst[e] : (e - N_EDGES);
  atomicAdd(&deg[d], 1);
}

__global__ __launch_bounds__(256) void scan1(const int* __restrict__ deg,
                                             int* __restrict__ rp,
                                             int* __restrict__ bsum) {
  __shared__ int sh[256];
  int t = threadIdx.x;
  int base = blockIdx.x * 1024 + t * 4;
  int v[4];
#pragma unroll
  for (int i = 0; i < 4; ++i) v[i] = (base + i < N_NODES) ? deg[base + i] : 0;
  int tsum = v[0] + v[1] + v[2] + v[3];
  sh[t] = tsum;
  __syncthreads();
  for (int off = 1; off < 256; off <<= 1) {
    int x = (t >= off) ? sh[t - off] : 0;
    __syncthreads();
    sh[t] += x;
    __syncthreads();
  }
  if (t == 255) bsum[blockIdx.x] = sh[255];
  int run = sh[t] - tsum;
#pragma unroll
  for (int i = 0; i < 4; ++i) {
    if (base + i < N_NODES) rp[base + i] = run;
    run += v[i];
  }
}

#define NBLK1 ((N_NODES + 1023) / 1024)  // 98

__global__ __launch_bounds__(128) void scan2(const int* __restrict__ bsum,
                                             int* __restrict__ boff) {
  __shared__ int sh[128];
  int t = threadIdx.x;
  int own = (t < NBLK1) ? bsum[t] : 0;
  sh[t] = own;
  __syncthreads();
  for (int off = 1; off < 128; off <<= 1) {
    int x = (t >= off) ? sh[t - off] : 0;
    __syncthreads();
    sh[t] += x;
    __syncthreads();
  }
  boff[t] = sh[t] - own;
}

__global__ __launch_bounds__(256) void scan3(int* __restrict__ rp,
                                             const int* __restrict__ boff,
                                             int* __restrict__ cursor) {
  int idx = blockIdx.x * 256 + threadIdx.x;
  if (idx < N_NODES) {
    int v = rp[idx] + boff[idx >> 10];
    rp[idx] = v;
    cursor[idx] = v;
  }
  if (idx == 0) rp[N_NODES] = TOT;
}

// scatter + fused edge-weight computation (packed fp16, scaled by e^-4)
__global__ __launch_bounds__(256) void scatter_edges(const int* __restrict__ esrc,
                                                     const int* __restrict__ edst,
                                                     const float* __restrict__ as_buf,
                                                     const float* __restrict__ ad_buf,
                                                     int* __restrict__ cursor,
                                                     int* __restrict__ csr_src,
                                                     uint2* __restrict__ wbuf) {
  int e = blockIdx.x * 256 + threadIdx.x;
  if (e >= TOT) return;
  int s, d;
  if (e < N_EDGES) { s = esrc[e]; d = edst[e]; }
  else { s = e - N_EDGES; d = s; }
  int p = atomicAdd(&cursor[d], 1);
  csr_src[p] = s;
  float4 a1 = *reinterpret_cast<const float4*>(as_buf + (size_t)s * NHEAD);
  float4 a2 = *reinterpret_cast<const float4*>(ad_buf + (size_t)d * NHEAD);
  float e0 = a1.x + a2.x; e0 = e0 > 0.f ? e0 : NEG_SLOPE * e0;
  float e1 = a1.y + a2.y; e1 = e1 > 0.f ? e1 : NEG_SLOPE * e1;
  float e2 = a1.z + a2.z; e2 = e2 > 0.f ? e2 : NEG_SLOPE * e2;
  float e3 = a1.w + a2.w; e3 = e3 > 0.f ? e3 : NEG_SLOPE * e3;
  // exp(e-4): shift cancels in softmax ratio, keeps fp16 in [e-5.5, e+8] safe range
  float w0 = __expf(e0 - 4.f), w1 = __expf(e1 - 4.f);
  float w2 = __expf(e2 - 4.f), w3 = __expf(e3 - 4.f);
  uint_t pk01 = __builtin_bit_cast(uint_t, __builtin_amdgcn_cvt_pkrtz(w0, w1));
  uint_t pk23 = __builtin_bit_cast(uint_t, __builtin_amdgcn_cvt_pkrtz(w2, w3));
  wbuf[p] = make_uint2(pk01, pk23);
}

// ---------------- fused softmax + aggregation: one wave per node ----------------
__global__ __launch_bounds__(256) void aggregate(const int* __restrict__ rp,
                                                 const int* __restrict__ csr_src,
                                                 const uint2* __restrict__ wbuf,
                                                 const uint2* __restrict__ Hp,
                                                 const float* __restrict__ bias,
                                                 float* __restrict__ out) {
  int n = blockIdx.x * 4 + (threadIdx.x >> 6);
  int lane = threadIdx.x & 63;
  if (n >= N_NODES) return;
  int beg = rp[n], end = rp[n + 1];
  float acc0 = 0.f, acc1 = 0.f, acc2 = 0.f, acc3 = 0.f;
  float den0 = 0.f, den1 = 0.f, den2 = 0.f, den3 = 0.f;
  int s_next = 0;
  uint2 w_next = make_uint2(0u, 0u);
  if (beg < end) { s_next = csr_src[beg]; w_next = wbuf[beg]; }
  for (int j = beg; j < end; ++j) {
    int s = s_next;
    uint2 wv = w_next;
    if (j + 1 < end) { s_next = csr_src[j + 1]; w_next = wbuf[j + 1]; }
    uint2 hv = Hp[(size_t)s * 64 + lane];
    h2v h01 = __builtin_bit_cast(h2v, hv.x);
    h2v h23 = __builtin_bit_cast(h2v, hv.y);
    h2v w01 = __builtin_bit_cast(h2v, wv.x);
    h2v w23 = __builtin_bit_cast(h2v, wv.y);
    acc0 += (float)w01.x * (float)h01.x;
    acc1 += (float)w01.y * (float)h01.y;
    acc2 += (float)w23.x * (float)h23.x;
    acc3 += (float)w23.y * (float)h23.y;
    den0 += (float)w01.x;
    den1 += (float)w01.y;
    den2 += (float)w23.x;
    den3 += (float)w23.y;
  }
  float r = acc0 / (den0 + 1e-30f) + acc1 / (den1 + 1e-30f) +
            acc2 / (den2 + 1e-30f) + acc3 / (den3 + 1e-30f);
  out[(size_t)n * CH + lane] = 0.25f * r + bias[lane];
}

extern "C" void kernel_launch(void* const* d_in, const int* in_sizes, int n_in,
                              void* d_out, int out_size, void* d_ws, size_t ws_size,
                              hipStream_t stream) {
  const float* x       = (const float*)d_in[0];
  const int*   eidx    = (const int*)d_in[1];
  const float* W       = (const float*)d_in[2];
  const float* att_src = (const float*)d_in[3];
  const float* att_dst = (const float*)d_in[4];
  const float* bias    = (const float*)d_in[5];
  float* out = (float*)d_out;

  uint2*    Hmp    = (uint2*)d_ws;                               // N*64 uint2 (51.2MB)
  uint2*    wbuf   = Hmp + (size_t)N_NODES * 64;                 // TOT uint2 (13.6MB)
  float*    as_buf = (float*)(wbuf + (size_t)TOT);               // N*4
  float*    ad_buf = as_buf + (size_t)N_NODES * NHEAD;           // N*4
  ushort_t* Wt     = (ushort_t*)(ad_buf + (size_t)N_NODES * NHEAD);  // 65536
  int*      deg    = (int*)(Wt + 65536);                         // N (reused as cursor)
  int*      rp     = deg + N_NODES;                              // N+1
  int*      bsum   = rp + N_NODES + 1;                           // 128
  int*      boff   = bsum + 128;                                 // 128
  int*      csr    = boff + 128;                                 // TOT

  const int* esrc = eidx;
  const int* edst = eidx + N_EDGES;

  conv_w<<<64, 256, 0, stream>>>(W, Wt);

  dim3 ggrid((N_NODES + GBM - 1) / GBM);
  gemm_mfma<<<ggrid, 256, 0, stream>>>(x, Wt, att_src, att_dst, Hmp, as_buf, ad_buf, N_NODES);

  hipMemsetAsync(deg, 0, (size_t)N_NODES * sizeof(int), stream);
  count_deg<<<(TOT + 255) / 256, 256, 0, stream>>>(edst, deg);
  scan1<<<NBLK1, 256, 0, stream>>>(deg, rp, bsum);
  scan2<<<1, 128, 0, stream>>>(bsum, boff);
  scan3<<<(N_NODES + 255) / 256, 256, 0, stream>>>(rp, boff, deg /*cursor*/);
  scatter_edges<<<(TOT + 255) / 256, 256, 0, stream>>>(esrc, edst, as_buf, ad_buf,
                                                       deg /*cursor*/, csr, wbuf);

  aggregate<<<(N_NODES + 3) / 4, 256, 0, stream>>>(rp, csr, wbuf, Hmp, bias, out);
}

// Round 5
// 354.198 us; speedup vs baseline: 3.5222x; 1.0574x over previous
//
#include <hip/hip_runtime.h>

#define N_NODES 100000
#define N_EDGES 1600000
#define TOT (N_EDGES + N_NODES)
#define IN_CH 256
#define NHEAD 4
#define CH 64
#define HC 256
#define NEG_SLOPE 0.2f

typedef _Float16 half8 __attribute__((ext_vector_type(8)));
typedef _Float16 h2v __attribute__((ext_vector_type(2)));
typedef float f32x4 __attribute__((ext_vector_type(4)));
typedef unsigned short ushort_t;
typedef unsigned int uint_t;

static __device__ __forceinline__ ushort_t f2h(float f) {
  _Float16 h = (_Float16)f;
  return __builtin_bit_cast(ushort_t, h);
}

// ---------------- W fp32 [K=256][N=256] -> Wt fp16 [N][K] ----------------
__global__ __launch_bounds__(256) void conv_w(const float* __restrict__ W,
                                              ushort_t* __restrict__ Wt) {
  int n = blockIdx.x * 4 + (threadIdx.x >> 6);
  int k0 = (threadIdx.x & 63) * 4;
  ushort4 u;
  u.x = f2h(W[(size_t)(k0 + 0) * HC + n]);
  u.y = f2h(W[(size_t)(k0 + 1) * HC + n]);
  u.z = f2h(W[(size_t)(k0 + 2) * HC + n]);
  u.w = f2h(W[(size_t)(k0 + 3) * HC + n]);
  *reinterpret_cast<ushort4*>(&Wt[(size_t)n * IN_CH + k0]) = u;
}

// ---------------- MFMA GEMM: Hmp = f16(X @ W), packed; fused attn dots ----------------
#define GBM 128
#define GBK 32
#define LDA 40  // 32 + 8 pad (halfs); row stride 80B (16B-aligned)

__global__ __launch_bounds__(256) void gemm_mfma(const float* __restrict__ X,
                                                 const ushort_t* __restrict__ Wt,
                                                 const float* __restrict__ att_src,
                                                 const float* __restrict__ att_dst,
                                                 uint2* __restrict__ Hmp,
                                                 float* __restrict__ as_out,
                                                 float* __restrict__ ad_out, int M) {
  __shared__ __align__(16) ushort_t As[GBM][LDA];
  __shared__ __align__(16) ushort_t Bs[HC][LDA];
  const int tid = threadIdx.x;
  const int lane = tid & 63;
  const int wid = tid >> 6;
  const int l16 = lane & 15;
  const int lhi = lane >> 4;
  const int row0 = blockIdx.x * GBM;

  f32x4 acc[2][16] = {};

  for (int k0 = 0; k0 < IN_CH; k0 += GBK) {
    {
      int r = tid >> 1;
      int c0 = (tid & 1) * 16;
      int gr = row0 + r;
      float4 v0, v1, v2, v3;
      if (gr < M) {
        const float4* p = reinterpret_cast<const float4*>(X + (size_t)gr * IN_CH + k0 + c0);
        v0 = p[0]; v1 = p[1]; v2 = p[2]; v3 = p[3];
      } else {
        v0 = v1 = v2 = v3 = make_float4(0.f, 0.f, 0.f, 0.f);
      }
      uint4 u0, u1;
      u0.x = __builtin_bit_cast(uint_t, __builtin_amdgcn_cvt_pkrtz(v0.x, v0.y));
      u0.y = __builtin_bit_cast(uint_t, __builtin_amdgcn_cvt_pkrtz(v0.z, v0.w));
      u0.z = __builtin_bit_cast(uint_t, __builtin_amdgcn_cvt_pkrtz(v1.x, v1.y));
      u0.w = __builtin_bit_cast(uint_t, __builtin_amdgcn_cvt_pkrtz(v1.z, v1.w));
      u1.x = __builtin_bit_cast(uint_t, __builtin_amdgcn_cvt_pkrtz(v2.x, v2.y));
      u1.y = __builtin_bit_cast(uint_t, __builtin_amdgcn_cvt_pkrtz(v2.z, v2.w));
      u1.z = __builtin_bit_cast(uint_t, __builtin_amdgcn_cvt_pkrtz(v3.x, v3.y));
      u1.w = __builtin_bit_cast(uint_t, __builtin_amdgcn_cvt_pkrtz(v3.z, v3.w));
      *reinterpret_cast<uint4*>(&As[r][c0]) = u0;
      *reinterpret_cast<uint4*>(&As[r][c0 + 8]) = u1;
    }
    {
      const uint4* p = reinterpret_cast<const uint4*>(Wt + (size_t)tid * IN_CH + k0);
      uint4 w0 = p[0], w1 = p[1];
      *reinterpret_cast<uint4*>(&Bs[tid][0]) = w0;
      *reinterpret_cast<uint4*>(&Bs[tid][8]) = w1;
      p = reinterpret_cast<const uint4*>(Wt + (size_t)tid * IN_CH + k0 + 16);
      uint4 w2 = p[0], w3 = p[1];
      *reinterpret_cast<uint4*>(&Bs[tid][16]) = w2;
      *reinterpret_cast<uint4*>(&Bs[tid][24]) = w3;
    }
    __syncthreads();
    half8 a0 = *reinterpret_cast<const half8*>(&As[wid * 32 + l16][lhi * 8]);
    half8 a1 = *reinterpret_cast<const half8*>(&As[wid * 32 + 16 + l16][lhi * 8]);
#pragma unroll
    for (int n = 0; n < 16; ++n) {
      half8 b = *reinterpret_cast<const half8*>(&Bs[n * 16 + l16][lhi * 8]);
      acc[0][n] = __builtin_amdgcn_mfma_f32_16x16x32_f16(a0, b, acc[0][n], 0, 0, 0);
      acc[1][n] = __builtin_amdgcn_mfma_f32_16x16x32_f16(a1, b, acc[1][n], 0, 0, 0);
    }
    __syncthreads();
  }

  float attS[16], attD[16];
#pragma unroll
  for (int n = 0; n < 16; ++n) {
    attS[n] = att_src[n * 16 + l16];
    attD[n] = att_dst[n * 16 + l16];
  }

#pragma unroll
  for (int m = 0; m < 2; ++m) {
#pragma unroll
    for (int r = 0; r < 4; ++r) {
      int grow = row0 + wid * 32 + m * 16 + lhi * 4 + r;
      if (grow < M) {
#pragma unroll
        for (int n2 = 0; n2 < 4; ++n2) {
          uint_t pk01 = __builtin_bit_cast(uint_t,
              __builtin_amdgcn_cvt_pkrtz(acc[m][n2][r], acc[m][n2 + 4][r]));
          uint_t pk23 = __builtin_bit_cast(uint_t,
              __builtin_amdgcn_cvt_pkrtz(acc[m][n2 + 8][r], acc[m][n2 + 12][r]));
          Hmp[(size_t)grow * 64 + n2 * 16 + l16] = make_uint2(pk01, pk23);
        }
        float s[4] = {0.f, 0.f, 0.f, 0.f}, d[4] = {0.f, 0.f, 0.f, 0.f};
#pragma unroll
        for (int h = 0; h < 4; ++h)
#pragma unroll
          for (int j = 0; j < 4; ++j) {
            s[h] += acc[m][h * 4 + j][r] * attS[h * 4 + j];
            d[h] += acc[m][h * 4 + j][r] * attD[h * 4 + j];
          }
#pragma unroll
        for (int off = 1; off < 16; off <<= 1)
#pragma unroll
          for (int h = 0; h < 4; ++h) {
            s[h] += __shfl_xor(s[h], off, 16);
            d[h] += __shfl_xor(d[h], off, 16);
          }
        if (l16 == 0) {
#pragma unroll
          for (int h = 0; h < 4; ++h) {
            as_out[(size_t)grow * 4 + h] = s[h];
            ad_out[(size_t)grow * 4 + h] = d[h];
          }
        }
      }
    }
  }
}

// ---------------- CSR build ----------------
__global__ __launch_bounds__(256) void init_deg(int* __restrict__ deg) {
  int i = blockIdx.x * 256 + threadIdx.x;
  if (i < N_NODES) deg[i] = 1;  // self-loop pre-counted
}

// vectorized: 4 edges/thread over real edges only
__global__ __launch_bounds__(256) void count_deg(const int* __restrict__ edst,
                                                 int* __restrict__ deg) {
  int t = blockIdx.x * 256 + threadIdx.x;
  if (t >= N_EDGES / 4) return;
  int4 d4 = reinterpret_cast<const int4*>(edst)[t];
  atomicAdd(&deg[d4.x], 1);
  atomicAdd(&deg[d4.y], 1);
  atomicAdd(&deg[d4.z], 1);
  atomicAdd(&deg[d4.w], 1);
}

__global__ __launch_bounds__(256) void scan1(const int* __restrict__ deg,
                                             int* __restrict__ rp,
                                             int* __restrict__ bsum) {
  __shared__ int sh[256];
  int t = threadIdx.x;
  int base = blockIdx.x * 1024 + t * 4;
  int v[4];
#pragma unroll
  for (int i = 0; i < 4; ++i) v[i] = (base + i < N_NODES) ? deg[base + i] : 0;
  int tsum = v[0] + v[1] + v[2] + v[3];
  sh[t] = tsum;
  __syncthreads();
  for (int off = 1; off < 256; off <<= 1) {
    int x = (t >= off) ? sh[t - off] : 0;
    __syncthreads();
    sh[t] += x;
    __syncthreads();
  }
  if (t == 255) bsum[blockIdx.x] = sh[255];
  int run = sh[t] - tsum;
#pragma unroll
  for (int i = 0; i < 4; ++i) {
    if (base + i < N_NODES) rp[base + i] = run;
    run += v[i];
  }
}

#define NBLK1 ((N_NODES + 1023) / 1024)  // 98

__global__ __launch_bounds__(128) void scan2(const int* __restrict__ bsum,
                                             int* __restrict__ boff) {
  __shared__ int sh[128];
  int t = threadIdx.x;
  int own = (t < NBLK1) ? bsum[t] : 0;
  sh[t] = own;
  __syncthreads();
  for (int off = 1; off < 128; off <<= 1) {
    int x = (t >= off) ? sh[t - off] : 0;
    __syncthreads();
    sh[t] += x;
    __syncthreads();
  }
  boff[t] = sh[t] - own;
}

__global__ __launch_bounds__(256) void scan3(int* __restrict__ rp,
                                             const int* __restrict__ boff,
                                             int* __restrict__ cursor) {
  int idx = blockIdx.x * 256 + threadIdx.x;
  if (idx < N_NODES) {
    int v = rp[idx] + boff[idx >> 10];
    rp[idx] = v;
    cursor[idx] = v;
  }
  if (idx == 0) rp[N_NODES] = TOT;
}

// scatter + fused edge-weight computation -> one 16B record {src, w01, w23, 0}
__global__ __launch_bounds__(256) void scatter_edges(const int* __restrict__ esrc,
                                                     const int* __restrict__ edst,
                                                     const float* __restrict__ as_buf,
                                                     const float* __restrict__ ad_buf,
                                                     int* __restrict__ cursor,
                                                     uint4* __restrict__ erec) {
  int e = blockIdx.x * 256 + threadIdx.x;
  if (e >= TOT) return;
  int s, d;
  if (e < N_EDGES) { s = esrc[e]; d = edst[e]; }
  else { s = e - N_EDGES; d = s; }
  int p = atomicAdd(&cursor[d], 1);
  float4 a1 = *reinterpret_cast<const float4*>(as_buf + (size_t)s * NHEAD);
  float4 a2 = *reinterpret_cast<const float4*>(ad_buf + (size_t)d * NHEAD);
  float e0 = a1.x + a2.x; e0 = e0 > 0.f ? e0 : NEG_SLOPE * e0;
  float e1 = a1.y + a2.y; e1 = e1 > 0.f ? e1 : NEG_SLOPE * e1;
  float e2 = a1.z + a2.z; e2 = e2 > 0.f ? e2 : NEG_SLOPE * e2;
  float e3 = a1.w + a2.w; e3 = e3 > 0.f ? e3 : NEG_SLOPE * e3;
  // exp(e-4): shift cancels in softmax ratio, keeps fp16 in safe range
  float w0 = __expf(e0 - 4.f), w1 = __expf(e1 - 4.f);
  float w2 = __expf(e2 - 4.f), w3 = __expf(e3 - 4.f);
  uint_t pk01 = __builtin_bit_cast(uint_t, __builtin_amdgcn_cvt_pkrtz(w0, w1));
  uint_t pk23 = __builtin_bit_cast(uint_t, __builtin_amdgcn_cvt_pkrtz(w2, w3));
  erec[p] = make_uint4((uint_t)s, pk01, pk23, 0u);
}

// ---------------- fused softmax + aggregation ----------------
// One wave per node; 2 edges per iteration (half-wave each, 32 lanes x 16B).
__global__ __launch_bounds__(256) void aggregate(const int* __restrict__ rp,
                                                 const uint4* __restrict__ erec,
                                                 const uint2* __restrict__ Hp,
                                                 const float* __restrict__ bias,
                                                 float* __restrict__ out) {
  int n = blockIdx.x * 4 + (threadIdx.x >> 6);
  int lane = threadIdx.x & 63;
  if (n >= N_NODES) return;
  const int half = lane >> 5;
  const uint_t off_lane = (uint_t)(lane & 31) << 4;  // byte offset within 512B row
  const char* __restrict__ Hb = (const char*)Hp;

  int beg = rp[n], end = rp[n + 1];  // end > beg (self-loop guaranteed)

  float acc[8] = {};  // {chA,chB} x {h0..h3}
  float den[4] = {};

  int idx0 = beg + half; if (idx0 > end - 1) idx0 = end - 1;
  uint4 rec = erec[idx0];

  for (int j = beg; j < end; j += 2) {
    uint4 cur = rec;
    // clamp-prefetch next pair (always in-bounds)
    int idn = j + 2 + half; if (idn > end - 1) idn = end - 1;
    rec = erec[idn];

    bool act = (j + half) < end;
    uint_t w01u = act ? cur.y : 0u;
    uint_t w23u = act ? cur.z : 0u;

    uint_t hoff = (cur.x << 9) | off_lane;
    uint4 hv = *reinterpret_cast<const uint4*>(Hb + hoff);

    h2v w01 = __builtin_bit_cast(h2v, w01u);
    h2v w23 = __builtin_bit_cast(h2v, w23u);
    h2v ha = __builtin_bit_cast(h2v, hv.x);  // chA heads 0,1
    h2v hb = __builtin_bit_cast(h2v, hv.y);  // chA heads 2,3
    h2v hc = __builtin_bit_cast(h2v, hv.z);  // chB heads 0,1
    h2v hd = __builtin_bit_cast(h2v, hv.w);  // chB heads 2,3

    acc[0] += (float)w01.x * (float)ha.x;
    acc[1] += (float)w01.y * (float)ha.y;
    acc[2] += (float)w23.x * (float)hb.x;
    acc[3] += (float)w23.y * (float)hb.y;
    acc[4] += (float)w01.x * (float)hc.x;
    acc[5] += (float)w01.y * (float)hc.y;
    acc[6] += (float)w23.x * (float)hd.x;
    acc[7] += (float)w23.y * (float)hd.y;
    den[0] += (float)w01.x;
    den[1] += (float)w01.y;
    den[2] += (float)w23.x;
    den[3] += (float)w23.y;
  }

  // combine the two half-wave partial sums
#pragma unroll
  for (int k = 0; k < 8; ++k) acc[k] += __shfl_xor(acc[k], 32, 64);
#pragma unroll
  for (int k = 0; k < 4; ++k) den[k] += __shfl_xor(den[k], 32, 64);

  if (lane < 32) {
    float i0 = 1.f / (den[0] + 1e-30f);
    float i1 = 1.f / (den[1] + 1e-30f);
    float i2 = 1.f / (den[2] + 1e-30f);
    float i3 = 1.f / (den[3] + 1e-30f);
    float2 b2 = *reinterpret_cast<const float2*>(bias + 2 * lane);
    float rA = 0.25f * (acc[0] * i0 + acc[1] * i1 + acc[2] * i2 + acc[3] * i3) + b2.x;
    float rB = 0.25f * (acc[4] * i0 + acc[5] * i1 + acc[6] * i2 + acc[7] * i3) + b2.y;
    *reinterpret_cast<float2*>(out + (size_t)n * CH + 2 * lane) = make_float2(rA, rB);
  }
}

extern "C" void kernel_launch(void* const* d_in, const int* in_sizes, int n_in,
                              void* d_out, int out_size, void* d_ws, size_t ws_size,
                              hipStream_t stream) {
  const float* x       = (const float*)d_in[0];
  const int*   eidx    = (const int*)d_in[1];
  const float* W       = (const float*)d_in[2];
  const float* att_src = (const float*)d_in[3];
  const float* att_dst = (const float*)d_in[4];
  const float* bias    = (const float*)d_in[5];
  float* out = (float*)d_out;

  uint2*    Hmp    = (uint2*)d_ws;                               // N*64 uint2 (51.2MB)
  uint4*    erec   = (uint4*)(Hmp + (size_t)N_NODES * 64);       // TOT uint4 (27.2MB)
  float*    as_buf = (float*)(erec + (size_t)TOT);               // N*4
  float*    ad_buf = as_buf + (size_t)N_NODES * NHEAD;           // N*4
  ushort_t* Wt     = (ushort_t*)(ad_buf + (size_t)N_NODES * NHEAD);  // 65536
  int*      deg    = (int*)(Wt + 65536);                         // N (reused as cursor)
  int*      rp     = deg + N_NODES;                              // N+1
  int*      bsum   = rp + N_NODES + 1;                           // 128
  int*      boff   = bsum + 128;                                 // 128

  const int* esrc = eidx;
  const int* edst = eidx + N_EDGES;

  conv_w<<<64, 256, 0, stream>>>(W, Wt);

  dim3 ggrid((N_NODES + GBM - 1) / GBM);
  gemm_mfma<<<ggrid, 256, 0, stream>>>(x, Wt, att_src, att_dst, Hmp, as_buf, ad_buf, N_NODES);

  init_deg<<<(N_NODES + 255) / 256, 256, 0, stream>>>(deg);
  count_deg<<<(N_EDGES / 4 + 255) / 256, 256, 0, stream>>>(edst, deg);
  scan1<<<NBLK1, 256, 0, stream>>>(deg, rp, bsum);
  scan2<<<1, 128, 0, stream>>>(bsum, boff);
  scan3<<<(N_NODES + 255) / 256, 256, 0, stream>>>(rp, boff, deg /*cursor*/);
  scatter_edges<<<(TOT + 255) / 256, 256, 0, stream>>>(esrc, edst, as_buf, ad_buf,
                                                       deg /*cursor*/, erec);

  aggregate<<<(N_NODES + 3) / 4, 256, 0, stream>>>(rp, erec, Hmp, bias, out);
}

// Round 6
// 338.388 us; speedup vs baseline: 3.6868x; 1.0467x over previous
//
#include <hip/hip_runtime.h>

#define N_NODES 100000
#define N_EDGES 1600000
#define TOT (N_EDGES + N_NODES)
#define IN_CH 256
#define NHEAD 4
#define CH 64
#define HC 256
#define NEG_SLOPE 0.2f

typedef _Float16 half8 __attribute__((ext_vector_type(8)));
typedef _Float16 h2v __attribute__((ext_vector_type(2)));
typedef float f32x4 __attribute__((ext_vector_type(4)));
typedef unsigned short ushort_t;
typedef unsigned int uint_t;

static __device__ __forceinline__ ushort_t f2h(float f) {
  _Float16 h = (_Float16)f;
  return __builtin_bit_cast(ushort_t, h);
}

// ---------------- W fp32 [K=256][N=256] -> Wt fp16 [N][K] ----------------
__global__ __launch_bounds__(256) void conv_w(const float* __restrict__ W,
                                              ushort_t* __restrict__ Wt) {
  int n = blockIdx.x * 4 + (threadIdx.x >> 6);
  int k0 = (threadIdx.x & 63) * 4;
  ushort4 u;
  u.x = f2h(W[(size_t)(k0 + 0) * HC + n]);
  u.y = f2h(W[(size_t)(k0 + 1) * HC + n]);
  u.z = f2h(W[(size_t)(k0 + 2) * HC + n]);
  u.w = f2h(W[(size_t)(k0 + 3) * HC + n]);
  *reinterpret_cast<ushort4*>(&Wt[(size_t)n * IN_CH + k0]) = u;
}

// ---------------- MFMA GEMM + fused attn dots + fused degree count ----------------
#define GBM 128
#define GBK 32
#define LDA 40  // 32 + 8 pad (halfs); row stride 80B (16B-aligned)

__global__ __launch_bounds__(256) void gemm_mfma(const float* __restrict__ X,
                                                 const ushort_t* __restrict__ Wt,
                                                 const float* __restrict__ att_src,
                                                 const float* __restrict__ att_dst,
                                                 uint2* __restrict__ Hmp,
                                                 float* __restrict__ as_out,
                                                 float* __restrict__ ad_out,
                                                 const int* __restrict__ edst,
                                                 int* __restrict__ deg, int M) {
  __shared__ __align__(16) ushort_t As[GBM][LDA];
  __shared__ __align__(16) ushort_t Bs[HC][LDA];
  const int tid = threadIdx.x;
  const int lane = tid & 63;
  const int wid = tid >> 6;
  const int l16 = lane & 15;
  const int lhi = lane >> 4;
  const int row0 = blockIdx.x * GBM;

  f32x4 acc[2][16] = {};

  for (int k0 = 0; k0 < IN_CH; k0 += GBK) {
    {
      int r = tid >> 1;
      int c0 = (tid & 1) * 16;
      int gr = row0 + r;
      float4 v0, v1, v2, v3;
      if (gr < M) {
        const float4* p = reinterpret_cast<const float4*>(X + (size_t)gr * IN_CH + k0 + c0);
        v0 = p[0]; v1 = p[1]; v2 = p[2]; v3 = p[3];
      } else {
        v0 = v1 = v2 = v3 = make_float4(0.f, 0.f, 0.f, 0.f);
      }
      uint4 u0, u1;
      u0.x = __builtin_bit_cast(uint_t, __builtin_amdgcn_cvt_pkrtz(v0.x, v0.y));
      u0.y = __builtin_bit_cast(uint_t, __builtin_amdgcn_cvt_pkrtz(v0.z, v0.w));
      u0.z = __builtin_bit_cast(uint_t, __builtin_amdgcn_cvt_pkrtz(v1.x, v1.y));
      u0.w = __builtin_bit_cast(uint_t, __builtin_amdgcn_cvt_pkrtz(v1.z, v1.w));
      u1.x = __builtin_bit_cast(uint_t, __builtin_amdgcn_cvt_pkrtz(v2.x, v2.y));
      u1.y = __builtin_bit_cast(uint_t, __builtin_amdgcn_cvt_pkrtz(v2.z, v2.w));
      u1.z = __builtin_bit_cast(uint_t, __builtin_amdgcn_cvt_pkrtz(v3.x, v3.y));
      u1.w = __builtin_bit_cast(uint_t, __builtin_amdgcn_cvt_pkrtz(v3.z, v3.w));
      *reinterpret_cast<uint4*>(&As[r][c0]) = u0;
      *reinterpret_cast<uint4*>(&As[r][c0 + 8]) = u1;
    }
    {
      const uint4* p = reinterpret_cast<const uint4*>(Wt + (size_t)tid * IN_CH + k0);
      uint4 w0 = p[0], w1 = p[1];
      *reinterpret_cast<uint4*>(&Bs[tid][0]) = w0;
      *reinterpret_cast<uint4*>(&Bs[tid][8]) = w1;
      p = reinterpret_cast<const uint4*>(Wt + (size_t)tid * IN_CH + k0 + 16);
      uint4 w2 = p[0], w3 = p[1];
      *reinterpret_cast<uint4*>(&Bs[tid][16]) = w2;
      *reinterpret_cast<uint4*>(&Bs[tid][24]) = w3;
    }
    __syncthreads();
    half8 a0 = *reinterpret_cast<const half8*>(&As[wid * 32 + l16][lhi * 8]);
    half8 a1 = *reinterpret_cast<const half8*>(&As[wid * 32 + 16 + l16][lhi * 8]);
#pragma unroll
    for (int n = 0; n < 16; ++n) {
      half8 b = *reinterpret_cast<const half8*>(&Bs[n * 16 + l16][lhi * 8]);
      acc[0][n] = __builtin_amdgcn_mfma_f32_16x16x32_f16(a0, b, acc[0][n], 0, 0, 0);
      acc[1][n] = __builtin_amdgcn_mfma_f32_16x16x32_f16(a1, b, acc[1][n], 0, 0, 0);
    }
    __syncthreads();
  }

  float attS[16], attD[16];
#pragma unroll
  for (int n = 0; n < 16; ++n) {
    attS[n] = att_src[n * 16 + l16];
    attD[n] = att_dst[n * 16 + l16];
  }

#pragma unroll
  for (int m = 0; m < 2; ++m) {
#pragma unroll
    for (int r = 0; r < 4; ++r) {
      int grow = row0 + wid * 32 + m * 16 + lhi * 4 + r;
      if (grow < M) {
#pragma unroll
        for (int n2 = 0; n2 < 4; ++n2) {
          uint_t pk01 = __builtin_bit_cast(uint_t,
              __builtin_amdgcn_cvt_pkrtz(acc[m][n2][r], acc[m][n2 + 4][r]));
          uint_t pk23 = __builtin_bit_cast(uint_t,
              __builtin_amdgcn_cvt_pkrtz(acc[m][n2 + 8][r], acc[m][n2 + 12][r]));
          Hmp[(size_t)grow * 64 + n2 * 16 + l16] = make_uint2(pk01, pk23);
        }
        float s[4] = {0.f, 0.f, 0.f, 0.f}, d[4] = {0.f, 0.f, 0.f, 0.f};
#pragma unroll
        for (int h = 0; h < 4; ++h)
#pragma unroll
          for (int j = 0; j < 4; ++j) {
            s[h] += acc[m][h * 4 + j][r] * attS[h * 4 + j];
            d[h] += acc[m][h * 4 + j][r] * attD[h * 4 + j];
          }
#pragma unroll
        for (int off = 1; off < 16; off <<= 1)
#pragma unroll
          for (int h = 0; h < 4; ++h) {
            s[h] += __shfl_xor(s[h], off, 16);
            d[h] += __shfl_xor(d[h], off, 16);
          }
        if (l16 == 0) {
#pragma unroll
          for (int h = 0; h < 4; ++h) {
            as_out[(size_t)grow * 4 + h] = s[h];
            ad_out[(size_t)grow * 4 + h] = d[h];
          }
        }
      }
    }
  }

  // ---- fused degree count (overlaps other blocks' MFMA): 2 int4 per thread ----
#pragma unroll
  for (int i = 0; i < 2; ++i) {
    int t = blockIdx.x * 512 + i * 256 + tid;
    if (t < N_EDGES / 4) {
      int4 d4 = reinterpret_cast<const int4*>(edst)[t];
      atomicAdd(&deg[d4.x], 1);
      atomicAdd(&deg[d4.y], 1);
      atomicAdd(&deg[d4.z], 1);
      atomicAdd(&deg[d4.w], 1);
    }
  }
}

// ---------------- CSR build (scans) ----------------
// scan1 adds the +1 self-loop per node inline.
__global__ __launch_bounds__(256) void scan1(const int* __restrict__ deg,
                                             int* __restrict__ rp,
                                             int* __restrict__ bsum) {
  __shared__ int sh[256];
  int t = threadIdx.x;
  int base = blockIdx.x * 1024 + t * 4;
  int v[4];
#pragma unroll
  for (int i = 0; i < 4; ++i) v[i] = (base + i < N_NODES) ? (deg[base + i] + 1) : 0;
  int tsum = v[0] + v[1] + v[2] + v[3];
  sh[t] = tsum;
  __syncthreads();
  for (int off = 1; off < 256; off <<= 1) {
    int x = (t >= off) ? sh[t - off] : 0;
    __syncthreads();
    sh[t] += x;
    __syncthreads();
  }
  if (t == 255) bsum[blockIdx.x] = sh[255];
  int run = sh[t] - tsum;
#pragma unroll
  for (int i = 0; i < 4; ++i) {
    if (base + i < N_NODES) rp[base + i] = run;
    run += v[i];
  }
}

#define NBLK1 ((N_NODES + 1023) / 1024)  // 98

__global__ __launch_bounds__(128) void scan2(const int* __restrict__ bsum,
                                             int* __restrict__ boff) {
  __shared__ int sh[128];
  int t = threadIdx.x;
  int own = (t < NBLK1) ? bsum[t] : 0;
  sh[t] = own;
  __syncthreads();
  for (int off = 1; off < 128; off <<= 1) {
    int x = (t >= off) ? sh[t - off] : 0;
    __syncthreads();
    sh[t] += x;
    __syncthreads();
  }
  boff[t] = sh[t] - own;
}

__global__ __launch_bounds__(256) void scan3(int* __restrict__ rp,
                                             const int* __restrict__ boff,
                                             int* __restrict__ cursor) {
  int idx = blockIdx.x * 256 + threadIdx.x;
  if (idx < N_NODES) {
    int v = rp[idx] + boff[idx >> 10];
    rp[idx] = v;
    cursor[idx] = v;
  }
  if (idx == 0) rp[N_NODES] = TOT;
}

// scatter + fused edge-weight computation -> one 16B record {src, w01, w23, 0}
__global__ __launch_bounds__(256) void scatter_edges(const int* __restrict__ esrc,
                                                     const int* __restrict__ edst,
                                                     const float* __restrict__ as_buf,
                                                     const float* __restrict__ ad_buf,
                                                     int* __restrict__ cursor,
                                                     uint4* __restrict__ erec) {
  int e = blockIdx.x * 256 + threadIdx.x;
  if (e >= TOT) return;
  int s, d;
  if (e < N_EDGES) { s = esrc[e]; d = edst[e]; }
  else { s = e - N_EDGES; d = s; }
  int p = atomicAdd(&cursor[d], 1);
  float4 a1 = *reinterpret_cast<const float4*>(as_buf + (size_t)s * NHEAD);
  float4 a2 = *reinterpret_cast<const float4*>(ad_buf + (size_t)d * NHEAD);
  float e0 = a1.x + a2.x; e0 = e0 > 0.f ? e0 : NEG_SLOPE * e0;
  float e1 = a1.y + a2.y; e1 = e1 > 0.f ? e1 : NEG_SLOPE * e1;
  float e2 = a1.z + a2.z; e2 = e2 > 0.f ? e2 : NEG_SLOPE * e2;
  float e3 = a1.w + a2.w; e3 = e3 > 0.f ? e3 : NEG_SLOPE * e3;
  // exp(e-4): shift cancels in softmax ratio, keeps fp16 in safe range
  float w0 = __expf(e0 - 4.f), w1 = __expf(e1 - 4.f);
  float w2 = __expf(e2 - 4.f), w3 = __expf(e3 - 4.f);
  uint_t pk01 = __builtin_bit_cast(uint_t, __builtin_amdgcn_cvt_pkrtz(w0, w1));
  uint_t pk23 = __builtin_bit_cast(uint_t, __builtin_amdgcn_cvt_pkrtz(w2, w3));
  erec[p] = make_uint4((uint_t)s, pk01, pk23, 0u);
}

// ---------------- fused softmax + aggregation ----------------
// One wave per node; 4 edges per iteration (2 half-wave records in flight).
__global__ __launch_bounds__(256) void aggregate(const int* __restrict__ rp,
                                                 const uint4* __restrict__ erec,
                                                 const uint2* __restrict__ Hp,
                                                 const float* __restrict__ bias,
                                                 float* __restrict__ out) {
  int n = blockIdx.x * 4 + (threadIdx.x >> 6);
  int lane = threadIdx.x & 63;
  if (n >= N_NODES) return;
  const int half = lane >> 5;
  const uint_t off_lane = (uint_t)(lane & 31) << 4;  // byte offset within 512B row
  const char* __restrict__ Hb = (const char*)Hp;

  int beg = rp[n], end = rp[n + 1];  // end > beg (self-loop guaranteed)
  const int last = end - 1;

  float acc[8] = {};  // {chA,chB} x {h0..h3}
  float den[4] = {};

  int ia = beg + half;     if (ia > last) ia = last;
  int ib = beg + 2 + half; if (ib > last) ib = last;
  uint4 rec_a = erec[ia];
  uint4 rec_b = erec[ib];

  for (int j = beg; j < end; j += 4) {
    uint4 cur_a = rec_a;
    uint4 cur_b = rec_b;
    // prefetch 2 pairs ahead (clamped, always in-bounds)
    ia = j + 4 + half; if (ia > last) ia = last;
    ib = j + 6 + half; if (ib > last) ib = last;
    rec_a = erec[ia];
    rec_b = erec[ib];

    // issue both gathers before consuming either
    uint_t hoff_a = (cur_a.x << 9) | off_lane;
    uint_t hoff_b = (cur_b.x << 9) | off_lane;
    uint4 hva = *reinterpret_cast<const uint4*>(Hb + hoff_a);
    uint4 hvb = *reinterpret_cast<const uint4*>(Hb + hoff_b);

    bool act_a = (j + half) < end;
    bool act_b = (j + 2 + half) < end;
    uint_t wa01u = act_a ? cur_a.y : 0u;
    uint_t wa23u = act_a ? cur_a.z : 0u;
    uint_t wb01u = act_b ? cur_b.y : 0u;
    uint_t wb23u = act_b ? cur_b.z : 0u;

    h2v wa01 = __builtin_bit_cast(h2v, wa01u);
    h2v wa23 = __builtin_bit_cast(h2v, wa23u);
    h2v wb01 = __builtin_bit_cast(h2v, wb01u);
    h2v wb23 = __builtin_bit_cast(h2v, wb23u);

    h2v haa = __builtin_bit_cast(h2v, hva.x);
    h2v hab = __builtin_bit_cast(h2v, hva.y);
    h2v hac = __builtin_bit_cast(h2v, hva.z);
    h2v had = __builtin_bit_cast(h2v, hva.w);

    acc[0] += (float)wa01.x * (float)haa.x;
    acc[1] += (float)wa01.y * (float)haa.y;
    acc[2] += (float)wa23.x * (float)hab.x;
    acc[3] += (float)wa23.y * (float)hab.y;
    acc[4] += (float)wa01.x * (float)hac.x;
    acc[5] += (float)wa01.y * (float)hac.y;
    acc[6] += (float)wa23.x * (float)had.x;
    acc[7] += (float)wa23.y * (float)had.y;
    den[0] += (float)wa01.x;
    den[1] += (float)wa01.y;
    den[2] += (float)wa23.x;
    den[3] += (float)wa23.y;

    h2v hba = __builtin_bit_cast(h2v, hvb.x);
    h2v hbb = __builtin_bit_cast(h2v, hvb.y);
    h2v hbc = __builtin_bit_cast(h2v, hvb.z);
    h2v hbd = __builtin_bit_cast(h2v, hvb.w);

    acc[0] += (float)wb01.x * (float)hba.x;
    acc[1] += (float)wb01.y * (float)hba.y;
    acc[2] += (float)wb23.x * (float)hbb.x;
    acc[3] += (float)wb23.y * (float)hbb.y;
    acc[4] += (float)wb01.x * (float)hbc.x;
    acc[5] += (float)wb01.y * (float)hbc.y;
    acc[6] += (float)wb23.x * (float)hbd.x;
    acc[7] += (float)wb23.y * (float)hbd.y;
    den[0] += (float)wb01.x;
    den[1] += (float)wb01.y;
    den[2] += (float)wb23.x;
    den[3] += (float)wb23.y;
  }

  // combine the two half-wave partial sums
#pragma unroll
  for (int k = 0; k < 8; ++k) acc[k] += __shfl_xor(acc[k], 32, 64);
#pragma unroll
  for (int k = 0; k < 4; ++k) den[k] += __shfl_xor(den[k], 32, 64);

  if (lane < 32) {
    float i0 = 1.f / (den[0] + 1e-30f);
    float i1 = 1.f / (den[1] + 1e-30f);
    float i2 = 1.f / (den[2] + 1e-30f);
    float i3 = 1.f / (den[3] + 1e-30f);
    float2 b2 = *reinterpret_cast<const float2*>(bias + 2 * lane);
    float rA = 0.25f * (acc[0] * i0 + acc[1] * i1 + acc[2] * i2 + acc[3] * i3) + b2.x;
    float rB = 0.25f * (acc[4] * i0 + acc[5] * i1 + acc[6] * i2 + acc[7] * i3) + b2.y;
    *reinterpret_cast<float2*>(out + (size_t)n * CH + 2 * lane) = make_float2(rA, rB);
  }
}

extern "C" void kernel_launch(void* const* d_in, const int* in_sizes, int n_in,
                              void* d_out, int out_size, void* d_ws, size_t ws_size,
                              hipStream_t stream) {
  const float* x       = (const float*)d_in[0];
  const int*   eidx    = (const int*)d_in[1];
  const float* W       = (const float*)d_in[2];
  const float* att_src = (const float*)d_in[3];
  const float* att_dst = (const float*)d_in[4];
  const float* bias    = (const float*)d_in[5];
  float* out = (float*)d_out;

  uint2*    Hmp    = (uint2*)d_ws;                               // N*64 uint2 (51.2MB)
  uint4*    erec   = (uint4*)(Hmp + (size_t)N_NODES * 64);       // TOT uint4 (27.2MB)
  float*    as_buf = (float*)(erec + (size_t)TOT);               // N*4
  float*    ad_buf = as_buf + (size_t)N_NODES * NHEAD;           // N*4
  ushort_t* Wt     = (ushort_t*)(ad_buf + (size_t)N_NODES * NHEAD);  // 65536
  int*      deg    = (int*)(Wt + 65536);                         // N (reused as cursor)
  int*      rp     = deg + N_NODES;                              // N+1
  int*      bsum   = rp + N_NODES + 1;                           // 128
  int*      boff   = bsum + 128;                                 // 128

  const int* esrc = eidx;
  const int* edst = eidx + N_EDGES;

  conv_w<<<64, 256, 0, stream>>>(W, Wt);
  hipMemsetAsync(deg, 0, (size_t)N_NODES * sizeof(int), stream);

  dim3 ggrid((N_NODES + GBM - 1) / GBM);
  gemm_mfma<<<ggrid, 256, 0, stream>>>(x, Wt, att_src, att_dst, Hmp, as_buf, ad_buf,
                                       edst, deg, N_NODES);

  scan1<<<NBLK1, 256, 0, stream>>>(deg, rp, bsum);
  scan2<<<1, 128, 0, stream>>>(bsum, boff);
  scan3<<<(N_NODES + 255) / 256, 256, 0, stream>>>(rp, boff, deg /*cursor*/);
  scatter_edges<<<(TOT + 255) / 256, 256, 0, stream>>>(esrc, edst, as_buf, ad_buf,
                                                       deg /*cursor*/, erec);

  aggregate<<<(N_NODES + 3) / 4, 256, 0, stream>>>(rp, erec, Hmp, bias, out);
}